// Round 10
// baseline (1754.372 us; speedup 1.0000x reference)
//
#include <hip/hip_runtime.h>
#include <math.h>

#define H 1024
#define BATCH 512
#define KSTEPS 96
#define KH ((long)KSTEPS * H)

typedef __attribute__((ext_vector_type(8))) short short8;
typedef __attribute__((ext_vector_type(16))) float f32x16;

__device__ __forceinline__ unsigned short f2bf(float x) {
    union { float f; unsigned int u; } v; v.f = x;
    unsigned int r = v.u + 0x7fffu + ((v.u >> 16) & 1u);
    return (unsigned short)(r >> 16);
}
__device__ __forceinline__ float bf2f(unsigned short h) {
    union { unsigned int u; float f; } v; v.u = ((unsigned int)h) << 16;
    return v.f;
}

// async global->LDS 16B/lane; dst wave-uniform base (HW adds lane*16)
__device__ __forceinline__ void glds16(const void* g, void* l) {
    __builtin_amdgcn_global_load_lds(
        (const __attribute__((address_space(1))) void*)g,
        (__attribute__((address_space(3))) void*)l, 16, 0, 0);
}
#define MEMFENCE asm volatile("" ::: "memory")

// ---------------------------------------------------------------------------
// Workspace layouts (32x32x16 MFMA fragment order):
//  blob0/blob1: [32 tc][64 by][2 s][2 jt][2 kg][64 l][8 e] bf16
//     J = by*64 + jt*32 + (l&31); g = J&3; j = J>>2
//     k = tc*32 + kg*16 + (l>>5)*8 + e
//     blob0 (step 1, x==0): g0=Whh_r, g1=Whh_z, g2=0, g3=Whh_n
//     blob1 (x==h): g0=Wih_r+Whh_r, g1=Wih_z+Whh_z, g2=Wih_n, g3=Whh_n
//  bcJ: [4096] f32 J-interleaved fused biases
//  hTa/hTb: [32 tc][4 bx][2 s][2 mh][2 mt][2 kg][64 l][8 e] bf16 hi/lo
//     m = bx*128 + mh*64 + mt*32 + (l&31); k = tc*32 + kg*16 + (l>>5)*8 + e
// ---------------------------------------------------------------------------

__global__ void prep_w(const float* __restrict__ wih,
                       const float* __restrict__ whh,
                       unsigned short* __restrict__ blob0,
                       unsigned short* __restrict__ blob1)
{
    const unsigned int f = blockIdx.x * 256 + threadIdx.x;  // 0..8388607
    const int e  = f & 7;
    const int l  = (f >> 3) & 63;
    const int kg = (f >> 9) & 1;
    const int jt = (f >> 10) & 1;
    const int s  = (f >> 11) & 1;
    const int by = (f >> 12) & 63;
    const int tc = (f >> 18) & 31;
    const int b  = blockIdx.y;      // blob select

    const int J = by * 64 + jt * 32 + (l & 31);
    const int g = J & 3;
    const long j = J >> 2;
    const long k = (long)tc * 32 + kg * 16 + (l >> 5) * 8 + e;

    float v = 0.f;
    if (b == 1) {
        if (g == 0)      v = wih[j*1024 + k]           + whh[j*1024 + k];
        else if (g == 1) v = wih[(1024+j)*1024 + k]    + whh[(1024+j)*1024 + k];
        else if (g == 2) v = wih[(2048+j)*1024 + k];
        else             v = whh[(2048+j)*1024 + k];
    } else {
        if (g == 0)      v = whh[j*1024 + k];
        else if (g == 1) v = whh[(1024+j)*1024 + k];
        else if (g == 2) v = 0.f;
        else             v = whh[(2048+j)*1024 + k];
    }
    const unsigned short hi = f2bf(v);
    unsigned short* blob = (b == 0) ? blob0 : blob1;
    blob[f] = (s == 0) ? hi : f2bf(v - bf2f(hi));
}

__global__ void prep_bcJ(const float* __restrict__ bih,
                         const float* __restrict__ bhh,
                         float* __restrict__ bcJ)
{
    const int J = blockIdx.x * 256 + threadIdx.x;   // 0..4095
    const int g = J & 3;
    const int j = J >> 2;
    float v;
    if (g == 0)      v = bih[j]        + bhh[j];
    else if (g == 1) v = bih[1024 + j] + bhh[1024 + j];
    else if (g == 2) v = bih[2048 + j];
    else             v = bhh[2048 + j];
    bcJ[J] = v;
}

// c [512][1024] fp32 -> hT fragment layout (hi/lo bf16)
__global__ void prep_h0(const float* __restrict__ cin,
                        unsigned short* __restrict__ hT)
{
    const unsigned int f = blockIdx.x * 256 + threadIdx.x;   // 0..1048575
    const int e  = f & 7;
    const int l  = (f >> 3) & 63;
    const int kg = (f >> 9) & 1;
    const int mt = (f >> 10) & 1;
    const int mh = (f >> 11) & 1;
    const int s  = (f >> 12) & 1;
    const int bx = (f >> 13) & 3;
    const int tc = (f >> 15) & 31;

    const long m = bx * 128 + mh * 64 + mt * 32 + (l & 31);
    const long k = (long)tc * 32 + kg * 16 + (l >> 5) * 8 + e;

    const float v = cin[m * 1024 + k];
    const unsigned short hi = f2bf(v);
    hT[f] = (s == 0) ? hi : f2bf(v - bf2f(hi));
}

// ---------------------------------------------------------------------------
// Fused GRU step. Grid 256 (1/CU), 512 threads (8 waves = 2/SIMD).
// Block tile 128m x 64J. Wave (gk 0..3, mh 0..1): 64 m x 64 J x K-quarter.
// 32x32x16 bf16 MFMA, 3-product hi/lo split. BK=32, 8 chunks/wave.
// W: 3 rotating LDS bufs per gk via glds16, staged 2 ahead, counted vmcnt(4)
// keeps W(c+2) in flight across the barrier. A (h-frags): VGPR 2-deep.
// Epilogue: 4-way split-K reduce in LDS + gate math -> out + next hT.
// ---------------------------------------------------------------------------
__global__ __launch_bounds__(512) void gru_step(
    const unsigned short* __restrict__ wblob,
    const unsigned short* __restrict__ hTr,
    unsigned short* __restrict__ hTw,
    const float* __restrict__ hprev, long hstride,
    const float* __restrict__ bcJ,
    float* __restrict__ outk)
{
    __shared__ __attribute__((aligned(16))) char smem[131072]; // W: 4gk x 3 x 8KB = 96KB; D: 128KB reuse

    const int tid  = threadIdx.x;
    const int lane = tid & 63;
    const int wv   = tid >> 6;        // 0..7
    const int gk   = wv >> 1;         // K-quarter 0..3
    const int mh   = wv & 1;          // m-half within 128

    const int id   = blockIdx.x;
    const int xcd  = id & 7;
    const int slot = id >> 3;
    const int by   = xcd * 8 + (slot & 7);   // 0..63  (J tile)
    const int bx   = slot >> 3;              // 0..3   (m tile)
    const long m0  = (long)bx * 128;

    const char* wsrc = (const char*)wblob + (long)by * 8192;   // + tc*524288
    const char* hsrc = (const char*)hTr + (long)bx * 16384;    // + tc*65536

    // ---- accumulators (bias folded into gk==0 init) ----
    f32x16 acc[2][2];   // [mt][jt]
    {
        const float b0 = (gk == 0) ? bcJ[by*64 + 0*32 + (lane & 31)] : 0.f;
        const float b1 = (gk == 0) ? bcJ[by*64 + 1*32 + (lane & 31)] : 0.f;
        #pragma unroll
        for (int mt = 0; mt < 2; ++mt)
            #pragma unroll
            for (int r = 0; r < 16; ++r) { acc[mt][0][r] = b0; acc[mt][1][r] = b1; }
    }

    short8 Aev[8], Aod[8];   // [ (s*2+mt)*2+kg ]

    auto loadA = [&](int c, short8* A) {
        const char* hs = hsrc + (long)(gk * 8 + c) * 65536;
        #pragma unroll
        for (int s = 0; s < 2; ++s)
            #pragma unroll
            for (int mt = 0; mt < 2; ++mt)
                #pragma unroll
                for (int kg = 0; kg < 2; ++kg)
                    A[(s*2+mt)*2+kg] = *(const short8*)
                        (hs + (long)((((s*2+mh)*2+mt)*2)+kg)*1024 + lane*16);
    };
    auto stageW = [&](int c) {
        const char* ws = wsrc + (long)(gk * 8 + c) * 524288;
        char* dst = smem + gk * 24576 + (c % 3) * 8192;
        #pragma unroll
        for (int o = 0; o < 4; ++o)
            glds16(ws + (mh*4+o)*1024 + lane*16, dst + (mh*4+o)*1024);
    };
    auto compute = [&](const char* wb, const short8* A) {
        #pragma unroll
        for (int kg = 0; kg < 2; ++kg) {
            const short8 bh0 = *(const short8*)(wb + (0*4 + 0*2 + kg)*1024 + lane*16);
            const short8 bh1 = *(const short8*)(wb + (0*4 + 1*2 + kg)*1024 + lane*16);
            const short8 bl0 = *(const short8*)(wb + (1*4 + 0*2 + kg)*1024 + lane*16);
            const short8 bl1 = *(const short8*)(wb + (1*4 + 1*2 + kg)*1024 + lane*16);
            const short8 ah0 = A[0*4 + 0*2 + kg];
            const short8 ah1 = A[0*4 + 1*2 + kg];
            const short8 al0 = A[1*4 + 0*2 + kg];
            const short8 al1 = A[1*4 + 1*2 + kg];
            // p0: Ah*Bh (4 independent chains)
            acc[0][0] = __builtin_amdgcn_mfma_f32_32x32x16_bf16(ah0, bh0, acc[0][0], 0, 0, 0);
            acc[0][1] = __builtin_amdgcn_mfma_f32_32x32x16_bf16(ah0, bh1, acc[0][1], 0, 0, 0);
            acc[1][0] = __builtin_amdgcn_mfma_f32_32x32x16_bf16(ah1, bh0, acc[1][0], 0, 0, 0);
            acc[1][1] = __builtin_amdgcn_mfma_f32_32x32x16_bf16(ah1, bh1, acc[1][1], 0, 0, 0);
            // p1: Al*Bh
            acc[0][0] = __builtin_amdgcn_mfma_f32_32x32x16_bf16(al0, bh0, acc[0][0], 0, 0, 0);
            acc[0][1] = __builtin_amdgcn_mfma_f32_32x32x16_bf16(al0, bh1, acc[0][1], 0, 0, 0);
            acc[1][0] = __builtin_amdgcn_mfma_f32_32x32x16_bf16(al1, bh0, acc[1][0], 0, 0, 0);
            acc[1][1] = __builtin_amdgcn_mfma_f32_32x32x16_bf16(al1, bh1, acc[1][1], 0, 0, 0);
            // p2: Ah*Bl
            acc[0][0] = __builtin_amdgcn_mfma_f32_32x32x16_bf16(ah0, bl0, acc[0][0], 0, 0, 0);
            acc[0][1] = __builtin_amdgcn_mfma_f32_32x32x16_bf16(ah0, bl1, acc[0][1], 0, 0, 0);
            acc[1][0] = __builtin_amdgcn_mfma_f32_32x32x16_bf16(ah1, bl0, acc[1][0], 0, 0, 0);
            acc[1][1] = __builtin_amdgcn_mfma_f32_32x32x16_bf16(ah1, bl1, acc[1][1], 0, 0, 0);
        }
    };

    // ---- prologue: A(0), W(0), W(1) ----
    loadA(0, Aev); MEMFENCE;
    stageW(0); MEMFENCE;
    stageW(1); MEMFENCE;
    asm volatile("s_waitcnt vmcnt(4)" ::: "memory");   // A0,W0 landed; W1 flying
    __builtin_amdgcn_s_barrier();

    #define CHUNK(c, Acur, Anext)                                          \
    {                                                                      \
        if ((c) < 7) { loadA((c)+1, Anext); MEMFENCE; }                    \
        if ((c) < 6) { stageW((c)+2); MEMFENCE; }                          \
        __builtin_amdgcn_sched_barrier(0);                                 \
        __builtin_amdgcn_s_setprio(1);                                     \
        compute(smem + gk*24576 + ((c)%3)*8192, Acur);                     \
        __builtin_amdgcn_s_setprio(0);                                     \
        if ((c) <= 5)      asm volatile("s_waitcnt vmcnt(4)" ::: "memory");\
        else if ((c) == 6) asm volatile("s_waitcnt vmcnt(0)" ::: "memory");\
        __builtin_amdgcn_s_barrier();                                      \
    }
    CHUNK(0, Aev, Aod) CHUNK(1, Aod, Aev) CHUNK(2, Aev, Aod) CHUNK(3, Aod, Aev)
    CHUNK(4, Aev, Aod) CHUNK(5, Aod, Aev) CHUNK(6, Aev, Aod) CHUNK(7, Aod, Aev)
    #undef CHUNK

    // ---- epilogue: dump partials, 4-way reduce, gates ----
    float* D = (float*)smem;   // [4 gk][128 m][64 J]
    #pragma unroll
    for (int mt = 0; mt < 2; ++mt)
        #pragma unroll
        for (int jt = 0; jt < 2; ++jt)
            #pragma unroll
            for (int r = 0; r < 16; ++r) {
                const int r32 = (r & 3) + 8 * (r >> 2) + 4 * (lane >> 5);
                const int m  = mh * 64 + mt * 32 + r32;
                const int J  = jt * 32 + (lane & 31);
                D[(gk * 128 + m) * 64 + J] = acc[mt][jt][r];
            }
    __syncthreads();

    #pragma unroll
    for (int it = 0; it < 4; ++it) {
        const int qi = it * 512 + tid;     // 0..2047
        const int jl = qi & 15;
        const int m  = qi >> 4;            // 0..127
        const float4 s0 = *(const float4*)&D[(0*128 + m)*64 + 4*jl];
        const float4 s1 = *(const float4*)&D[(1*128 + m)*64 + 4*jl];
        const float4 s2 = *(const float4*)&D[(2*128 + m)*64 + 4*jl];
        const float4 s3 = *(const float4*)&D[(3*128 + m)*64 + 4*jl];
        const float gr = s0.x + s1.x + s2.x + s3.x;
        const float gz = s0.y + s1.y + s2.y + s3.y;
        const float gi = s0.z + s1.z + s2.z + s3.z;
        const float gh = s0.w + s1.w + s2.w + s3.w;

        const long mg = m0 + m;
        const long j  = (long)by * 16 + jl;

        const float hp = hprev[mg * hstride + j];
        const float rr = 1.f / (1.f + expf(-gr));
        const float zz = 1.f / (1.f + expf(-gz));
        const float nn = tanhf(fmaf(rr, gh, gi));
        const float o  = nn + zz * (hp - nn);

        outk[mg * KH + j] = o;

        // hT writeback (next step's A fragment layout)
        const unsigned short hi = f2bf(o);
        const unsigned short lo = f2bf(o - bf2f(hi));
        const int kk  = (int)j;            // hidden index = next-step K index
        const int tc2 = kk >> 5;
        const int kg2 = (kk >> 4) & 1;
        const int lh  = (kk >> 3) & 1;
        const int e2  = kk & 7;
        const int mh2 = (m >> 6) & 1;
        const int mt2 = (m >> 5) & 1;
        const int row = m & 31;
        const long ub = ((((((long)tc2*4 + bx)*2 + 0)*2 + mh2)*2 + mt2)*2 + kg2)*512
                      + (lh*32 + row)*8 + e2;
        hTw[ub]        = hi;
        hTw[ub + 4096] = lo;     // s-stride = 2*2*2*512 = 4096 ushorts
    }
}

// ---------------------------------------------------------------------------
extern "C" void kernel_launch(void* const* d_in, const int* in_sizes, int n_in,
                              void* d_out, int out_size, void* d_ws, size_t ws_size,
                              hipStream_t stream)
{
    const float* c   = (const float*)d_in[0];
    // d_in[1] = K (fixed 96)
    const float* wih = (const float*)d_in[2];
    const float* whh = (const float*)d_in[3];
    const float* bih = (const float*)d_in[4];
    const float* bhh = (const float*)d_in[5];
    float* out = (float*)d_out;

    unsigned short* blob0 = (unsigned short*)d_ws;            // 8.39M ushort
    unsigned short* blob1 = blob0 + 8388608L;
    float*          bcJ   = (float*)(blob1 + 8388608L);       // 4096 f32
    unsigned short* hTa   = (unsigned short*)(bcJ + 4096);    // 1M ushort
    unsigned short* hTb   = hTa + 1048576L;

    prep_w  <<<dim3(32768, 2), 256, 0, stream>>>(wih, whh, blob0, blob1);
    prep_bcJ<<<dim3(16),       256, 0, stream>>>(bih, bhh, bcJ);
    prep_h0 <<<dim3(4096),     256, 0, stream>>>(c, hTa);

    for (int k = 0; k < KSTEPS; ++k) {
        const unsigned short* wb  = (k == 0) ? blob0 : blob1;
        const unsigned short* hTr = (k & 1) ? hTb : hTa;
        unsigned short*       hTw = (k & 1) ? hTa : hTb;
        const float* hprev = (k == 0) ? c : (out + (long)(k - 1) * H);
        const long hstride = (k == 0) ? (long)H : KH;
        gru_step<<<dim3(256), 512, 0, stream>>>(wb, hTr, hTw, hprev, hstride,
                                                bcJ, out + (long)k * H);
    }
}